// Round 3
// baseline (917.442 us; speedup 1.0000x reference)
//
#include <hip/hip_runtime.h>

// GCN layer: out = log_softmax( mean_agg( norm * (x@W) ) + b )
// N=100000, F=256, C=64, E=3.2M (derived from in_sizes at runtime).
// edge_index arrives as int32 (harness converts integer inputs to int).
//
// ws layout (floats):
//   xw  [N*C] : x @ W
//   deg [N]   : in-degree + 1 (self loop)
//   dis [N]   : rsqrt(deg)
// agg accumulates directly in d_out (initialized by k_gemm epilogue).

#define C_DIM 64
#define F_DIM 256

__global__ void k_deg_init(float* __restrict__ deg, int N) {
    int i = blockIdx.x * blockDim.x + threadIdx.x;
    if (i < N) deg[i] = 1.0f;   // self loop
}

__global__ void k_deg_count(const int* __restrict__ ei, float* __restrict__ deg,
                            int E) {
    int stride = gridDim.x * blockDim.x;
    for (int e = blockIdx.x * blockDim.x + threadIdx.x; e < E; e += stride) {
        int d = ei[E + e];                 // dst row
        atomicAdd(&deg[d], 1.0f);
    }
}

__global__ void k_dis(const float* __restrict__ deg, float* __restrict__ dis, int N) {
    int i = blockIdx.x * blockDim.x + threadIdx.x;
    if (i < N) dis[i] = rsqrtf(deg[i]);    // deg >= 1 always (self loop)
}

// Tiled fp32 GEMM: xw = x @ W, plus epilogue agg = dis^2 * xw (self-loop msg).
// Block = 256 threads, 64 rows/block. K chunked by 64.
// Thread t: channels c = (t&15)*4 .. +3, rows (t>>4)*4 .. +3  -> 4x4 acc.
__launch_bounds__(256, 4)
__global__ void k_gemm(const float* __restrict__ x, const float* __restrict__ W,
                       const float* __restrict__ dis,
                       float* __restrict__ xw, float* __restrict__ agg, int N) {
    // xs stride 68 floats: row-to-row = 272B -> float4-aligned, 2-way-max bank alias (free)
    __shared__ float xs[64 * 68];
    __shared__ float ws[64 * 64];
    const int t   = threadIdx.x;
    const int c16 = t & 15;     // channel group: c = c16*4
    const int rg  = t >> 4;     // row group: rows rg*4 .. rg*4+3
    const int row0 = blockIdx.x * 64;

    float acc[4][4] = {};

    for (int kk = 0; kk < F_DIM / 64; ++kk) {
        // --- stage x chunk: 64 rows x 64 f ---
        {
            int r  = t >> 2;
            int fq = (t & 3) * 16;
            int grow = row0 + r;
            float4 v0, v1, v2, v3;
            if (grow < N) {
                const float* src = x + (long long)grow * F_DIM + kk * 64 + fq;
                v0 = *(const float4*)(src + 0);
                v1 = *(const float4*)(src + 4);
                v2 = *(const float4*)(src + 8);
                v3 = *(const float4*)(src + 12);
            } else {
                v0 = v1 = v2 = v3 = make_float4(0.f, 0.f, 0.f, 0.f);
            }
            float4* dstp = (float4*)&xs[r * 68 + fq];
            dstp[0] = v0; dstp[1] = v1; dstp[2] = v2; dstp[3] = v3;
        }
        // --- stage W chunk: 64 f x 64 c ---
        {
            int f  = t >> 2;
            int cq = (t & 3) * 16;
            const float* src = W + (long long)(kk * 64 + f) * C_DIM + cq;
            float4* dstp = (float4*)&ws[f * 64 + cq];
            dstp[0] = *(const float4*)(src + 0);
            dstp[1] = *(const float4*)(src + 4);
            dstp[2] = *(const float4*)(src + 8);
            dstp[3] = *(const float4*)(src + 12);
        }
        __syncthreads();

        const float4* xs4 = (const float4*)xs;  // row stride 17 float4
        const float4* ws4 = (const float4*)ws;  // f stride 16 float4
        #pragma unroll
        for (int f4 = 0; f4 < 16; ++f4) {
            float xr[4][4];
            #pragma unroll
            for (int k = 0; k < 4; ++k) {
                float4 v = xs4[(rg * 4 + k) * 17 + f4];
                xr[k][0] = v.x; xr[k][1] = v.y; xr[k][2] = v.z; xr[k][3] = v.w;
            }
            #pragma unroll
            for (int j = 0; j < 4; ++j) {
                float4 wv = ws4[(f4 * 4 + j) * 16 + c16];
                #pragma unroll
                for (int k = 0; k < 4; ++k) {
                    acc[k][0] += xr[k][j] * wv.x;
                    acc[k][1] += xr[k][j] * wv.y;
                    acc[k][2] += xr[k][j] * wv.z;
                    acc[k][3] += xr[k][j] * wv.w;
                }
            }
        }
        __syncthreads();
    }

    const int c = c16 * 4;
    #pragma unroll
    for (int k = 0; k < 4; ++k) {
        int row = row0 + rg * 4 + k;
        if (row < N) {
            float d  = dis[row];
            float d2 = d * d;
            float4 v = make_float4(acc[k][0], acc[k][1], acc[k][2], acc[k][3]);
            *(float4*)&xw[(size_t)row * C_DIM + c]  = v;
            float4 a = make_float4(v.x * d2, v.y * d2, v.z * d2, v.w * d2);
            *(float4*)&agg[(size_t)row * C_DIM + c] = a;
        }
    }
}

// One wave per edge (grid-stride): lane = channel.
__launch_bounds__(256)
__global__ void k_edge(const int* __restrict__ ei, const float* __restrict__ xw,
                       const float* __restrict__ dis, float* __restrict__ agg,
                       int E) {
    const int lane = threadIdx.x & 63;
    int wid = (blockIdx.x * blockDim.x + threadIdx.x) >> 6;
    int nw  = (gridDim.x * blockDim.x) >> 6;
    for (int e = wid; e < E; e += nw) {
        int s = ei[e];
        int d = ei[E + e];
        float w = dis[s] * dis[d];
        float v = xw[(size_t)s * C_DIM + lane] * w;
        atomicAdd(&agg[(size_t)d * C_DIM + lane], v);
    }
}

// One wave per node: out = log_softmax(agg/deg + b), in place (agg == out).
__launch_bounds__(256)
__global__ void k_final(float* __restrict__ agg, const float* __restrict__ deg,
                        const float* __restrict__ b, int N) {
    const int lane = threadIdx.x & 63;
    int row = blockIdx.x * (blockDim.x >> 6) + (threadIdx.x >> 6);
    if (row >= N) return;
    float v = agg[(size_t)row * C_DIM + lane] / deg[row] + b[lane];
    float m = v;
    #pragma unroll
    for (int off = 32; off >= 1; off >>= 1) m = fmaxf(m, __shfl_xor(m, off, 64));
    float ex = expf(v - m);
    float s = ex;
    #pragma unroll
    for (int off = 32; off >= 1; off >>= 1) s += __shfl_xor(s, off, 64);
    agg[(size_t)row * C_DIM + lane] = v - m - logf(s);
}

extern "C" void kernel_launch(void* const* d_in, const int* in_sizes, int n_in,
                              void* d_out, int out_size, void* d_ws, size_t ws_size,
                              hipStream_t stream) {
    const float* x  = (const float*)d_in[0];
    const int*   ei = (const int*)d_in[1];
    const float* W  = (const float*)d_in[2];
    const float* b  = (const float*)d_in[3];

    const int C = in_sizes[3];            // 64
    const int F = in_sizes[2] / C;        // 256
    const int N = in_sizes[0] / F;        // 100000
    const int E = in_sizes[1] / 2;        // 3.2M

    float* agg = (float*)d_out;           // accumulate in the output buffer
    float* ws  = (float*)d_ws;
    float* xw  = ws;
    float* deg = ws + (size_t)N * C;
    float* dis = deg + N;

    hipLaunchKernelGGL(k_deg_init, dim3((N + 255) / 256), dim3(256), 0, stream, deg, N);
    hipLaunchKernelGGL(k_deg_count, dim3(2048), dim3(256), 0, stream, ei, deg, E);
    hipLaunchKernelGGL(k_dis, dim3((N + 255) / 256), dim3(256), 0, stream, deg, dis, N);
    hipLaunchKernelGGL(k_gemm, dim3((N + 63) / 64), dim3(256), 0, stream,
                       x, W, dis, xw, agg, N);
    hipLaunchKernelGGL(k_edge, dim3(4096), dim3(256), 0, stream, ei, xw, dis, agg, E);
    hipLaunchKernelGGL(k_final, dim3((N + 3) / 4), dim3(256), 0, stream,
                       agg, deg, b, N);
}

// Round 5
// 542.148 us; speedup vs baseline: 1.6922x; 1.6922x over previous
//
#include <hip/hip_runtime.h>

// GCN layer: out = log_softmax( mean_agg( norm * (x@W) ) + b )
// N=100000, F=256, C=64, E=3.2M (derived from in_sizes at runtime).
//
// Strategy (atomic-free aggregation):
//   1. degE[d] = in-degree (int, real edges)           [atomic count]
//   2. rowptr  = exclusive_scan(degE)                  [3-kernel scan]
//   3. col     = edges bucketed by dst                 [scatter w/ cnt atomics]
//   4. xw      = x @ W                                 [tiled fp32 GEMM]
//   5. per-dst wave: gather+normalize+mean+bias+log_softmax -> d_out, no atomics
// Fallback to the round-3 atomic path if ws_size is too small.

#define C_DIM 64
#define F_DIM 256

// ---------------- shared kernels ----------------

__global__ void k_zero2(int* __restrict__ a, int* __restrict__ b, int N) {
    int i = blockIdx.x * blockDim.x + threadIdx.x;
    if (i < N) { a[i] = 0; b[i] = 0; }
}

__global__ void k_count(const int* __restrict__ ei, int* __restrict__ degE, int E) {
    int stride = gridDim.x * blockDim.x;
    for (int e = blockIdx.x * blockDim.x + threadIdx.x; e < E; e += stride)
        atomicAdd(&degE[ei[E + e]], 1);
}

__global__ void k_dis2(const int* __restrict__ degE, float* __restrict__ dis, int N) {
    int i = blockIdx.x * blockDim.x + threadIdx.x;
    if (i < N) dis[i] = rsqrtf((float)(degE[i] + 1));   // +1 self loop
}

// Tiled fp32 GEMM: xw = x @ W. Block = 256 threads, 64 rows/block, K chunk 64.
__launch_bounds__(256, 4)
__global__ void k_gemm(const float* __restrict__ x, const float* __restrict__ W,
                       float* __restrict__ xw, int N) {
    __shared__ float xs[64 * 68];
    __shared__ float ws[64 * 64];
    const int t   = threadIdx.x;
    const int c16 = t & 15;
    const int rg  = t >> 4;
    const int row0 = blockIdx.x * 64;

    float acc[4][4] = {};

    for (int kk = 0; kk < F_DIM / 64; ++kk) {
        {
            int r  = t >> 2;
            int fq = (t & 3) * 16;
            int grow = row0 + r;
            float4 v0, v1, v2, v3;
            if (grow < N) {
                const float* src = x + (long long)grow * F_DIM + kk * 64 + fq;
                v0 = *(const float4*)(src + 0);
                v1 = *(const float4*)(src + 4);
                v2 = *(const float4*)(src + 8);
                v3 = *(const float4*)(src + 12);
            } else {
                v0 = v1 = v2 = v3 = make_float4(0.f, 0.f, 0.f, 0.f);
            }
            float4* dstp = (float4*)&xs[r * 68 + fq];
            dstp[0] = v0; dstp[1] = v1; dstp[2] = v2; dstp[3] = v3;
        }
        {
            int f  = t >> 2;
            int cq = (t & 3) * 16;
            const float* src = W + (long long)(kk * 64 + f) * C_DIM + cq;
            float4* dstp = (float4*)&ws[f * 64 + cq];
            dstp[0] = *(const float4*)(src + 0);
            dstp[1] = *(const float4*)(src + 4);
            dstp[2] = *(const float4*)(src + 8);
            dstp[3] = *(const float4*)(src + 12);
        }
        __syncthreads();

        const float4* xs4 = (const float4*)xs;
        const float4* ws4 = (const float4*)ws;
        #pragma unroll
        for (int f4 = 0; f4 < 16; ++f4) {
            float xr[4][4];
            #pragma unroll
            for (int k = 0; k < 4; ++k) {
                float4 v = xs4[(rg * 4 + k) * 17 + f4];
                xr[k][0] = v.x; xr[k][1] = v.y; xr[k][2] = v.z; xr[k][3] = v.w;
            }
            #pragma unroll
            for (int j = 0; j < 4; ++j) {
                float4 wv = ws4[(f4 * 4 + j) * 16 + c16];
                #pragma unroll
                for (int k = 0; k < 4; ++k) {
                    acc[k][0] += xr[k][j] * wv.x;
                    acc[k][1] += xr[k][j] * wv.y;
                    acc[k][2] += xr[k][j] * wv.z;
                    acc[k][3] += xr[k][j] * wv.w;
                }
            }
        }
        __syncthreads();
    }

    const int c = c16 * 4;
    #pragma unroll
    for (int k = 0; k < 4; ++k) {
        int row = row0 + rg * 4 + k;
        if (row < N) {
            float4 v = make_float4(acc[k][0], acc[k][1], acc[k][2], acc[k][3]);
            *(float4*)&xw[(size_t)row * C_DIM + c] = v;
        }
    }
}

// ---------------- CSR build ----------------

__global__ void k_scan_blk(const int* __restrict__ degE, int* __restrict__ excl,
                           int* __restrict__ bsum, int N) {
    __shared__ int sm[1024];
    const int tid = threadIdx.x;
    int i = blockIdx.x * 1024 + tid;
    int v = (i < N) ? degE[i] : 0;
    sm[tid] = v;
    __syncthreads();
    for (int off = 1; off < 1024; off <<= 1) {
        int t = (tid >= off) ? sm[tid - off] : 0;
        __syncthreads();
        sm[tid] += t;
        __syncthreads();
    }
    int incl = sm[tid];
    if (i < N) excl[i] = incl - v;
    if (tid == 1023) bsum[blockIdx.x] = incl;
}

__global__ void k_scan_top(int* __restrict__ bs, int nblk) {
    __shared__ int sm[128];
    const int tid = threadIdx.x;
    int v = (tid < nblk) ? bs[tid] : 0;
    sm[tid] = v;
    __syncthreads();
    for (int off = 1; off < 128; off <<= 1) {
        int t = (tid >= off) ? sm[tid - off] : 0;
        __syncthreads();
        sm[tid] += t;
        __syncthreads();
    }
    if (tid < nblk) bs[tid] = sm[tid] - v;   // in-place exclusive
}

__global__ void k_scan_add(const int* __restrict__ excl, const int* __restrict__ bs,
                           int* __restrict__ rowptr, int N, int E) {
    int i = blockIdx.x * blockDim.x + threadIdx.x;
    if (i < N) rowptr[i] = excl[i] + bs[i >> 10];
    if (i == 0) rowptr[N] = E;
}

__global__ void k_scatter(const int* __restrict__ ei, const int* __restrict__ rowptr,
                          int* __restrict__ cnt, int* __restrict__ col, int E) {
    int stride = gridDim.x * blockDim.x;
    for (int e = blockIdx.x * blockDim.x + threadIdx.x; e < E; e += stride) {
        int s = ei[e];
        int d = ei[E + e];
        int p = atomicAdd(&cnt[d], 1);
        col[rowptr[d] + p] = s;
    }
}

// One wave per dst node: gather + normalize + mean + bias + log_softmax.
__launch_bounds__(256)
__global__ void k_agg(const int* __restrict__ rowptr, const int* __restrict__ col,
                      const float* __restrict__ xw, const float* __restrict__ dis,
                      const float* __restrict__ b, float* __restrict__ out, int N) {
    const int lane = threadIdx.x & 63;
    int row = blockIdx.x * 4 + (threadIdx.x >> 6);
    if (row >= N) return;
    const int start = rowptr[row], end = rowptr[row + 1];
    const float dd = dis[row];
    float acc = dd * xw[(size_t)row * C_DIM + lane];   // self-loop (x dd below)
    int i = start;
    for (; i + 4 <= end; i += 4) {
        int s0 = col[i], s1 = col[i + 1], s2 = col[i + 2], s3 = col[i + 3];
        float w0 = dis[s0], w1 = dis[s1], w2 = dis[s2], w3 = dis[s3];
        acc += w0 * xw[(size_t)s0 * C_DIM + lane];
        acc += w1 * xw[(size_t)s1 * C_DIM + lane];
        acc += w2 * xw[(size_t)s2 * C_DIM + lane];
        acc += w3 * xw[(size_t)s3 * C_DIM + lane];
    }
    for (; i < end; ++i) {
        int s = col[i];
        acc += dis[s] * xw[(size_t)s * C_DIM + lane];
    }
    acc *= dd;
    float v = acc / (float)(end - start + 1) + b[lane];
    float m = v;
    #pragma unroll
    for (int off = 32; off >= 1; off >>= 1) m = fmaxf(m, __shfl_xor(m, off, 64));
    float ex = expf(v - m);
    float ssum = ex;
    #pragma unroll
    for (int off = 32; off >= 1; off >>= 1) ssum += __shfl_xor(ssum, off, 64);
    out[(size_t)row * C_DIM + lane] = v - m - logf(ssum);
}

// ---------------- fallback (atomic) path ----------------

__global__ void k_selfloop(const float* __restrict__ xw, const float* __restrict__ dis,
                           float* __restrict__ agg, int NC) {
    int i = blockIdx.x * blockDim.x + threadIdx.x;
    if (i < NC) {
        float d = dis[i >> 6];
        agg[i] = d * d * xw[i];
    }
}

__launch_bounds__(256)
__global__ void k_edge(const int* __restrict__ ei, const float* __restrict__ xw,
                       const float* __restrict__ dis, float* __restrict__ agg, int E) {
    const int lane = threadIdx.x & 63;
    int wid = (blockIdx.x * blockDim.x + threadIdx.x) >> 6;
    int nw  = (gridDim.x * blockDim.x) >> 6;
    for (int e = wid; e < E; e += nw) {
        int s = ei[e];
        int d = ei[E + e];
        float w = dis[s] * dis[d];
        atomicAdd(&agg[(size_t)d * C_DIM + lane], xw[(size_t)s * C_DIM + lane] * w);
    }
}

__launch_bounds__(256)
__global__ void k_final2(float* __restrict__ agg, const int* __restrict__ degE,
                         const float* __restrict__ b, int N) {
    const int lane = threadIdx.x & 63;
    int row = blockIdx.x * 4 + (threadIdx.x >> 6);
    if (row >= N) return;
    float v = agg[(size_t)row * C_DIM + lane] / (float)(degE[row] + 1) + b[lane];
    float m = v;
    #pragma unroll
    for (int off = 32; off >= 1; off >>= 1) m = fmaxf(m, __shfl_xor(m, off, 64));
    float ex = expf(v - m);
    float ssum = ex;
    #pragma unroll
    for (int off = 32; off >= 1; off >>= 1) ssum += __shfl_xor(ssum, off, 64);
    agg[(size_t)row * C_DIM + lane] = v - m - logf(ssum);
}

// ---------------- launch ----------------

extern "C" void kernel_launch(void* const* d_in, const int* in_sizes, int n_in,
                              void* d_out, int out_size, void* d_ws, size_t ws_size,
                              hipStream_t stream) {
    const float* x  = (const float*)d_in[0];
    const int*   ei = (const int*)d_in[1];
    const float* W  = (const float*)d_in[2];
    const float* b  = (const float*)d_in[3];

    const int C = in_sizes[3];            // 64
    const int F = in_sizes[2] / C;        // 256
    const int N = in_sizes[0] / F;        // 100000
    const int E = in_sizes[1] / 2;        // 3.2M

    float* out = (float*)d_out;
    char*  wsb = (char*)d_ws;

    const int nblk = (N + 1023) / 1024;

    // ws layout (4B units)
    size_t off = 0;
    float* xw     = (float*)(wsb + off); off += (size_t)N * C * 4;
    float* dis    = (float*)(wsb + off); off += (size_t)N * 4;
    int*   degE   = (int*)(wsb + off);   off += (size_t)N * 4;
    int*   rowptr = (int*)(wsb + off);   off += ((size_t)N + 1) * 4;
    int*   cnt    = (int*)(wsb + off);   off += (size_t)N * 4;
    int*   excl   = (int*)(wsb + off);   off += (size_t)nblk * 1024 * 4;
    int*   bsum   = (int*)(wsb + off);   off += 128 * 4;
    int*   col    = (int*)(wsb + off);   off += (size_t)E * 4;
    const bool csr_ok = (off <= ws_size) && (nblk <= 128);

    const dim3 B256(256);
    const dim3 gN((N + 255) / 256);
    const dim3 gNC(((size_t)N * C + 255) / 256);

    if (csr_ok) {
        hipLaunchKernelGGL(k_zero2,    gN, B256, 0, stream, degE, cnt, N);
        hipLaunchKernelGGL(k_count,    dim3(2048), B256, 0, stream, ei, degE, E);
        hipLaunchKernelGGL(k_dis2,     gN, B256, 0, stream, degE, dis, N);
        hipLaunchKernelGGL(k_scan_blk, dim3(nblk), dim3(1024), 0, stream, degE, excl, bsum, N);
        hipLaunchKernelGGL(k_scan_top, dim3(1), dim3(128), 0, stream, bsum, nblk);
        hipLaunchKernelGGL(k_scan_add, gN, B256, 0, stream, excl, bsum, rowptr, N, E);
        hipLaunchKernelGGL(k_gemm,     dim3((N + 63) / 64), B256, 0, stream, x, W, xw, N);
        hipLaunchKernelGGL(k_scatter,  dim3(2048), B256, 0, stream, ei, rowptr, cnt, col, E);
        hipLaunchKernelGGL(k_agg,      dim3((N + 3) / 4), B256, 0, stream,
                           rowptr, col, xw, dis, b, out, N);
    } else {
        // fallback: atomic aggregation into d_out
        hipLaunchKernelGGL(k_zero2,    gN, B256, 0, stream, degE, degE, N);
        hipLaunchKernelGGL(k_count,    dim3(2048), B256, 0, stream, ei, degE, E);
        hipLaunchKernelGGL(k_dis2,     gN, B256, 0, stream, degE, dis, N);
        hipLaunchKernelGGL(k_gemm,     dim3((N + 63) / 64), B256, 0, stream, x, W, xw, N);
        hipLaunchKernelGGL(k_selfloop, gNC, B256, 0, stream, xw, dis, out, N * C);
        hipLaunchKernelGGL(k_edge,     dim3(4096), B256, 0, stream, ei, xw, dis, out, E);
        hipLaunchKernelGGL(k_final2,   dim3((N + 3) / 4), B256, 0, stream, out, degE, b, N);
    }
}